// Round 5
// baseline (50.584 us; speedup 1.0000x reference)
//
#include <hip/hip_runtime.h>
#include <hip/hip_fp16.h>

// Problem constants (from setup_inputs): L=8, H=32, M=8192, R=16, D=128, S=4096
constexpr int H = 32;
constexpr int S = 4096;
constexpr int D = 128;
constexpr float EPSF = 1e-12f;
constexpr long NROWS = 2L * H * S;       // 262144 rows total (K side then V side)

typedef float vfloat4 __attribute__((ext_vector_type(4)));

// ---------------- Pass 1: norm table (read-dominated) ----------------
// norms[row] = f32(f16(||states_row||_2)) for all 2*H*S rows. 1 MB in d_ws.
// Wave w owns 32 consecutive rows; half-wave per row, float4 per lane.
__global__ void VLKV_norms_kernel(const float* __restrict__ K,
                                  const float* __restrict__ V,
                                  float* __restrict__ norms) {
    const int tid  = threadIdx.x;
    const int lane = tid & 63;
    const int wv   = tid >> 6;
    const int half = lane >> 5;
    const int li   = lane & 31;

    const long w     = (long)blockIdx.x * (blockDim.x >> 6) + wv;
    const long row0  = w * 32;
    const int  side  = (int)(row0 >> 17);           // H*S = 2^17
    const long srow0 = row0 & (long)(H * S - 1);

    const float* src = (side == 0 ? K : V) + (srow0 + half) * (long)D + li * 4;

#pragma unroll 4
    for (int i = 0; i < 16; ++i) {
        const float4 x = *(const float4*)(src + (long)i * 2 * D);
        float ss = x.x * x.x + x.y * x.y + x.z * x.z + x.w * x.w;
#pragma unroll
        for (int m = 1; m < 32; m <<= 1) ss += __shfl_xor(ss, m);  // within half-wave
        if (li == 0) {
            norms[row0 + i * 2 + half] =
                __half2float(__float2half(sqrtf(ss)));
        }
    }
}

// ---------------- Pass 2: pure write stream ----------------
// out[row, d] = norms[row] * f32(f16(last_row_normalized[head, d]))
// Wave w owns 32 consecutive output rows (all one head). Reads: 512 B last
// row (L2-warm) + 128 B norms. Writes: 16 KB nontemporal stream.
__global__ void VLKV_write_kernel(const float* __restrict__ K,
                                  const float* __restrict__ V,
                                  const float* __restrict__ norms,
                                  float* __restrict__ out) {
    const int tid  = threadIdx.x;
    const int lane = tid & 63;
    const int wv   = tid >> 6;
    const int half = lane >> 5;
    const int li   = lane & 31;

    const long w     = (long)blockIdx.x * (blockDim.x >> 6) + wv;
    const long row0  = w * 32;
    const int  side  = (int)(row0 >> 17);
    const long srow0 = row0 & (long)(H * S - 1);
    const int  h     = (int)(srow0 >> 12);          // S = 2^12

    const float* base = (side == 0 ? K : V);

    // Normalized last row of this head, f16-rounded, in registers.
    const float4 lv = *(const float4*)(base + ((long)h * S + (S - 1)) * D + li * 4);
    float lss = lv.x * lv.x + lv.y * lv.y + lv.z * lv.z + lv.w * lv.w;
#pragma unroll
    for (int m = 1; m < 32; m <<= 1) lss += __shfl_xor(lss, m);
    const float inv = 1.0f / (sqrtf(lss) + EPSF);
    float4 ln;
    ln.x = __half2float(__float2half(lv.x * inv));
    ln.y = __half2float(__float2half(lv.y * inv));
    ln.z = __half2float(__float2half(lv.z * inv));
    ln.w = __half2float(__float2half(lv.w * inv));

    // Lane j (j<32) holds norms[row0 + j]; broadcast per iteration via shfl.
    const float nv = norms[row0 + (lane & 31)];     // lanes 32..63 load dup — harmless

    float* dst = out + (row0 + half) * (long)D + li * 4;

#pragma unroll 8
    for (int i = 0; i < 16; ++i) {
        const float nh = __shfl(nv, i * 2 + half);  // src lane in [0,31]
        vfloat4 o;
        o.x = nh * ln.x;
        o.y = nh * ln.y;
        o.z = nh * ln.z;
        o.w = nh * ln.w;
        __builtin_nontemporal_store(o, (vfloat4*)(dst + (long)i * 2 * D));
    }
}

// ---------------- Fallback: round-3 fused kernel (if ws too small) ----------------
__global__ void VLKV_fused_kernel(const float* __restrict__ K,
                                  const float* __restrict__ V,
                                  float* __restrict__ out) {
    const int tid  = threadIdx.x;
    const int lane = tid & 63;
    const int wv   = tid >> 6;
    const int half = lane >> 5;
    const int li   = lane & 31;

    const long w     = (long)blockIdx.x * (blockDim.x >> 6) + wv;
    const long row0  = w * 32;
    const int  side  = (int)(row0 >> 17);
    const long srow0 = row0 & (long)(H * S - 1);
    const int  h     = (int)(srow0 >> 12);

    const float* base = (side == 0 ? K : V);

    const float4 lv = *(const float4*)(base + ((long)h * S + (S - 1)) * D + li * 4);
    float lss = lv.x * lv.x + lv.y * lv.y + lv.z * lv.z + lv.w * lv.w;
#pragma unroll
    for (int m = 1; m < 32; m <<= 1) lss += __shfl_xor(lss, m);
    const float inv = 1.0f / (sqrtf(lss) + EPSF);
    float4 ln;
    ln.x = __half2float(__float2half(lv.x * inv));
    ln.y = __half2float(__float2half(lv.y * inv));
    ln.z = __half2float(__float2half(lv.z * inv));
    ln.w = __half2float(__float2half(lv.w * inv));

    const float* src = base + (srow0 + half) * (long)D + li * 4;
    float*       dst = out  + (row0  + half) * (long)D + li * 4;

#pragma unroll 4
    for (int i = 0; i < 16; ++i) {
        const float4 x = *(const float4*)(src + (long)i * 2 * D);
        float ss = x.x * x.x + x.y * x.y + x.z * x.z + x.w * x.w;
#pragma unroll
        for (int m = 1; m < 32; m <<= 1) ss += __shfl_xor(ss, m);
        const float nh = __half2float(__float2half(sqrtf(ss)));
        vfloat4 o;
        o.x = nh * ln.x;
        o.y = nh * ln.y;
        o.z = nh * ln.z;
        o.w = nh * ln.w;
        __builtin_nontemporal_store(o, (vfloat4*)(dst + (long)i * 2 * D));
    }
}

extern "C" void kernel_launch(void* const* d_in, const int* in_sizes, int n_in,
                              void* d_out, int out_size, void* d_ws, size_t ws_size,
                              hipStream_t stream) {
    const float* K = (const float*)d_in[0];   // key_states   [1,H,S,D] f32
    const float* V = (const float*)d_in[1];   // value_states [1,H,S,D] f32
    float* out = (float*)d_out;               // [2][H][S][D] f32 (k_full ++ v_full)

    const size_t norms_bytes = (size_t)NROWS * sizeof(float);   // 1 MiB
    if (ws_size >= norms_bytes) {
        float* norms = (float*)d_ws;
        VLKV_norms_kernel<<<2048, 256, 0, stream>>>(K, V, norms);
        VLKV_write_kernel<<<2048, 256, 0, stream>>>(K, V, norms, out);
    } else {
        VLKV_fused_kernel<<<2048, 256, 0, stream>>>(K, V, out);
    }
}

// Round 6
// 45.191 us; speedup vs baseline: 1.1193x; 1.1193x over previous
//
#include <hip/hip_runtime.h>
#include <hip/hip_fp16.h>

// Problem constants (from setup_inputs): L=8, H=32, M=8192, R=16, D=128, S=4096
constexpr int H = 32;
constexpr int S = 4096;
constexpr int D = 128;
constexpr float EPSF = 1e-12f;

typedef float vfloat4 __attribute__((ext_vector_type(4)));

// Fused single kernel (round-4 structure, unroll 8).
// out[side,h,s,d] = f32(f16(||row(side,h,s)||)) * f32(f16(row(side,h,S-1,d)/(||row(side,h,S-1)||+eps)))
//
// Wave w owns rows [w*32, w*32+32) of the 2*H*S = 262144 global rows; all 32
// share one (side, head) since 32 | S. Each 32-lane half-wave computes the
// head's f16-rounded normalized last row once into registers, then streams
// 16 rows: contiguous 16 KB read + 16 KB nontemporal write per wave.
//
// Roofline note: 268 MB logical traffic / 6.29 TB/s copy ceiling = 42.6 us
// floor; this kernel measured 44.8 us at unroll 4 (95% of ceiling).
__global__ void VLKV_fused_kernel(const float* __restrict__ K,
                                  const float* __restrict__ V,
                                  float* __restrict__ out) {
    const int tid  = threadIdx.x;
    const int lane = tid & 63;
    const int wv   = tid >> 6;            // wave index in block
    const int half = lane >> 5;           // which row of each pair
    const int li   = lane & 31;           // lane within the 32-lane row group

    const long w     = (long)blockIdx.x * (blockDim.x >> 6) + wv;
    const long row0  = w * 32;                      // first global row of this wave
    const int  side  = (int)(row0 >> 17);           // H*S = 2^17
    const long srow0 = row0 & (long)(H * S - 1);    // row within side
    const int  h     = (int)(srow0 >> 12);          // head (S = 2^12)

    const float* base = (side == 0 ? K : V);

    // ---- startup: f16-rounded normalized last row of this head, in registers ----
    const float4 lv = *(const float4*)(base + ((long)h * S + (S - 1)) * D + li * 4);
    float lss = lv.x * lv.x + lv.y * lv.y + lv.z * lv.z + lv.w * lv.w;
#pragma unroll
    for (int m = 1; m < 32; m <<= 1) lss += __shfl_xor(lss, m);   // within 32-lane half
    const float inv = 1.0f / (sqrtf(lss) + EPSF);
    float4 ln;
    ln.x = __half2float(__float2half(lv.x * inv));
    ln.y = __half2float(__float2half(lv.y * inv));
    ln.z = __half2float(__float2half(lv.z * inv));
    ln.w = __half2float(__float2half(lv.w * inv));

    // ---- main loop: 16 row-pairs, contiguous streams, 8 loads in flight ----
    const float* src = base + (srow0 + half) * (long)D + li * 4;
    float*       dst = out  + (row0  + half) * (long)D + li * 4;

#pragma unroll 8
    for (int i = 0; i < 16; ++i) {
        const float4 x = *(const float4*)(src + (long)i * 2 * D);
        float ss = x.x * x.x + x.y * x.y + x.z * x.z + x.w * x.w;
#pragma unroll
        for (int m = 1; m < 32; m <<= 1) ss += __shfl_xor(ss, m);
        const float nh = __half2float(__float2half(sqrtf(ss)));

        vfloat4 o;
        o.x = nh * ln.x;
        o.y = nh * ln.y;
        o.z = nh * ln.z;
        o.w = nh * ln.w;
        __builtin_nontemporal_store(o, (vfloat4*)(dst + (long)i * 2 * D));
    }
}

extern "C" void kernel_launch(void* const* d_in, const int* in_sizes, int n_in,
                              void* d_out, int out_size, void* d_ws, size_t ws_size,
                              hipStream_t stream) {
    const float* K = (const float*)d_in[0];   // key_states   [1,H,S,D] f32
    const float* V = (const float*)d_in[1];   // value_states [1,H,S,D] f32
    float* out = (float*)d_out;               // [2][H][S][D] f32 (k_full ++ v_full)

    // 8192 waves x 32 rows/wave = 262144 rows = 2*H*S, exact cover.
    VLKV_fused_kernel<<<2048, 256, 0, stream>>>(K, V, out);
}